// Round 6
// baseline (548.175 us; speedup 1.0000x reference)
//
#include <hip/hip_runtime.h>
#include <cstdint>
#include <cstddef>

typedef __attribute__((ext_vector_type(8))) short short8_t;
typedef __attribute__((ext_vector_type(4))) float f32x4;

#define DEV __device__ __forceinline__

DEV unsigned short f2bf(float f) {
    unsigned u = __float_as_uint(f);
    u += 0x7FFFu + ((u >> 16) & 1u);   // round-to-nearest-even
    return (unsigned short)(u >> 16);
}

// ---------------------------------------------------------------------------
// Weight packing: fp32 row-major (K x N) -> bf16 MFMA-B fragment order.
// ---------------------------------------------------------------------------
__global__ void pack_weights(const float* W1, const float* W2,
                             const float* Wp1, const float* Wp2,
                             const float* Ws1, const float* Ws2, const float* Ws3,
                             const float* Wg1, const float* Wg2, const float* Wg3,
                             const float* Wgate, unsigned short* out)
{
    int c = blockIdx.x * 256 + threadIdx.x;
    if (c >= 176640) return;
    const float* src; int K, N; size_t dstoff; int lc = c;
    if      (c <  16384) { src = W1;  K=256; N=512; dstoff = 0; }
    else if (c <  32768) { lc = c-16384;  src = W2;  K=512; N=256; dstoff = 131072; }
    else if (c <  98304) { lc = c-32768;  int p = lc/8192; lc -= p*8192;
                           src = Wp1 + (size_t)p*65536; K=256; N=256;
                           dstoff = 262144 + (size_t)p*65536; }
    else if (c < 110592) { lc = c-98304;  int p = lc/1536; lc -= p*1536;
                           src = Wp2 + (size_t)p*10240; K=256; N=40;
                           dstoff = 786432 + (size_t)p*12288; }
    else if (c < 126976) { lc = c-110592; src = Ws1; K=256; N=512; dstoff = 884736; }
    else if (c < 143360) { lc = c-126976; src = Ws2; K=512; N=256; dstoff = 1015808; }
    else if (c < 147456) { lc = c-143360; src = Ws3; K=256; N=128; dstoff = 1146880; }
    else if (c < 155648) { lc = c-147456; src = Wg1; K=128; N=512; dstoff = 1179648; }
    else if (c < 172032) { lc = c-155648; src = Wg2; K=512; N=256; dstoff = 1245184; }
    else if (c < 176128) { lc = c-172032; src = Wg3; K=256; N=128; dstoff = 1376256; }
    else                 { lc = c-176128; src = Wgate; K=256; N=8;  dstoff = 1409024; }
    int lane = lc & 63, tkb = lc >> 6;
    int KB = K >> 5;
    int kb = tkb % KB, t = tkb / KB;
    int n  = t*16 + (lane & 15);
    int k0 = kb*32 + (lane >> 4)*8;
    unsigned short e[8];
#pragma unroll
    for (int j = 0; j < 8; ++j) {
        float v = (n < N) ? src[(size_t)(k0 + j)*N + n] : 0.f;
        e[j] = f2bf(v);
    }
    uint4 o;
    o.x = (unsigned)e[0] | ((unsigned)e[1] << 16);
    o.y = (unsigned)e[2] | ((unsigned)e[3] << 16);
    o.z = (unsigned)e[4] | ((unsigned)e[5] << 16);
    o.w = (unsigned)e[6] | ((unsigned)e[7] << 16);
    *reinterpret_cast<uint4*>(out + dstoff + (size_t)lc*8) = o;
}

// ---------------------------------------------------------------------------
struct Params {
    const float *obs, *actions;
    const float *b1, *b2, *bp1, *bp2, *bs1, *bs2, *bs3, *bg1, *bg2, *bg3, *bgate;
    const unsigned short *W1p, *W2p, *Wp1p, *Wp2p, *Ws1p, *Ws2p, *Ws3p,
                         *Wg1p, *Wg2p, *Wg3p, *Wgatep;
    float* out;
};

// A from LDS (bf16, stride xs elems), B from packed global. 32-bit flat
// addressing (R5 evidence: removes address-chain spills under (512,4)).
template<int NTW, int NMT, int NKB>
DEV void mfma_tiles(const unsigned short* X, int xs,
                    const unsigned short* wp, int nkbtot, int kbstart,
                    int nt0, f32x4 (&acc)[NTW][NMT])
{
    const int lane = threadIdx.x & 63;
    const int q = lane >> 4, r = lane & 15;
    const short8_t* __restrict__ W8 = (const short8_t*)wp;
    const short8_t* __restrict__ X8 = (const short8_t*)X;
    const int xrow = xs >> 3;
    const int bbase = (nt0*nkbtot + kbstart)*64 + lane;
#pragma unroll
    for (int kb = 0; kb < NKB; ++kb) {
        short8_t a[NMT];
#pragma unroll
        for (int mt = 0; mt < NMT; ++mt)
            a[mt] = X8[(r + 16*mt)*xrow + kb*4 + q];
#pragma unroll
        for (int t = 0; t < NTW; ++t) {
            short8_t b = W8[bbase + (t*nkbtot + kb)*64];
#pragma unroll
            for (int mt = 0; mt < NMT; ++mt)
                acc[t][mt] = __builtin_amdgcn_mfma_f32_16x16x32_bf16(a[mt], b, acc[t][mt], 0, 0, 0);
        }
    }
}

// A built in-register from fp32 global obs (rows b0+mt*16+r, cols colbase+...)
template<int NTW, int NKB>
DEV void mfma_obsA2(const float* obs, int b0, int colbase,
                    const unsigned short* wp, int nkbtot, int nt0,
                    f32x4 (&acc)[NTW][2])
{
    const int lane = threadIdx.x & 63;
    const int q = lane >> 4, r = lane & 15;
    const short8_t* __restrict__ W8 = (const short8_t*)wp;
    const int bbase = nt0*nkbtot*64 + lane;
#pragma unroll
    for (int kb = 0; kb < NKB; ++kb) {
        short8_t a[2];
#pragma unroll
        for (int mt = 0; mt < 2; ++mt) {
            const float* s = obs + (size_t)(b0 + mt*16 + r)*384 + colbase + kb*32 + q*8;
            float4 v0 = *reinterpret_cast<const float4*>(s);
            float4 v1 = *reinterpret_cast<const float4*>(s + 4);
            a[mt] = short8_t{ (short)f2bf(v0.x),(short)f2bf(v0.y),(short)f2bf(v0.z),(short)f2bf(v0.w),
                              (short)f2bf(v1.x),(short)f2bf(v1.y),(short)f2bf(v1.z),(short)f2bf(v1.w) };
        }
#pragma unroll
        for (int t = 0; t < NTW; ++t) {
            short8_t b = W8[bbase + (t*nkbtot + kb)*64];
#pragma unroll
            for (int mt = 0; mt < 2; ++mt)
                acc[t][mt] = __builtin_amdgcn_mfma_f32_16x16x32_bf16(a[mt], b, acc[t][mt], 0, 0, 0);
        }
    }
}

// store one n-tile (both m-tiles) to bf16 LDS, bias + optional leaky-relu
DEV void store2_bf16(const f32x4 (&a)[2], unsigned short* dst, int os, int col0,
                     const float* bias, int Nreal, bool lrelu)
{
    const int lane = threadIdx.x & 63;
    const int q = lane >> 4, r = lane & 15;
    const int col = col0 + r;
    float bv = (col < Nreal) ? bias[col] : 0.f;
#pragma unroll
    for (int mt = 0; mt < 2; ++mt)
#pragma unroll
        for (int i = 0; i < 4; ++i) {
            float v = a[mt][i] + bv;
            if (lrelu) v = v > 0.f ? v : 0.01f*v;
            dst[(mt*16 + q*4 + i)*os + col] = f2bf(v);
        }
}

// ---------------------------------------------------------------------------
// 512 threads = 8 waves, 32 rows/block, 3 rotating LDS buffers, interleaved
// independent chains to fatten barrier intervals. LDS 62976 B -> 2 blocks/CU.
// (512,4) hard 128-reg budget (R2/R5 evidence: only tier reaching 16 waves/CU).
__global__ __launch_bounds__(512, 4) void actor_fused(Params p)
{
    __shared__ __align__(16) unsigned char smem[62976];
    unsigned short* X     = (unsigned short*)(smem);           // 32x264: xStat -> g1h1 -> bufA
    unsigned short* H1    = (unsigned short*)(smem + 16896);   // 32x264
    unsigned short* H2    = (unsigned short*)(smem + 33792);   // 32x264
    float*          psbuf = (float*)(smem + 50688);            // 32x48 f32
    float*          sums  = (float*)(smem + 56832);            // 32x40 f32
    float*          wgate = (float*)(smem + 61952);            // 32x8 f32

    const int tid  = threadIdx.x;
    const int wave = tid >> 6;
    const int lane = tid & 63, q = lane >> 4, r = lane & 15;
    const int b0   = blockIdx.x * 32;

    // ---- P1: load obs stat cols -> X ---------------------------------------
    for (int i = tid; i < 32*64; i += 512) {
        int rr = i >> 6, c4 = i & 63;
        const float4 v = *reinterpret_cast<const float4*>(p.obs + (size_t)(b0 + rr)*384 + c4*4);
        unsigned short* d = X + rr*264 + c4*4;
        d[0]=f2bf(v.x); d[1]=f2bf(v.y); d[2]=f2bf(v.z); d[3]=f2bf(v.w);
    }
    __syncthreads();

    f32x4 acc1[2][2] = {};   // s1-chain (W2) accumulator, lives I2..I6
    f32x4 acc2[2][2] = {};   // s2-chain (Ws2) accumulator, lives I2..I3

    // ---- I1: W1-h0 + Ws1-h0 from X ------------------------------------------
    {
        f32x4 t1[2][2] = {}, t2[2][2] = {};
        mfma_tiles<2,2,8>(X, 264, p.W1p,  8, 0, 2*wave,      t1);
        mfma_tiles<2,2,8>(X, 264, p.Ws1p, 8, 0, 2*wave,      t2);
        // H1/H2 fresh: no pre-store barrier needed
#pragma unroll
        for (int t = 0; t < 2; ++t) {
            store2_bf16(t1[t], H1, 264, (2*wave + t)*16, p.b1,  256, true);
            store2_bf16(t2[t], H2, 264, (2*wave + t)*16, p.bs1, 256, true);
        }
        __syncthreads();
    }

    // ---- I2: W2(k0-255 from H1) + Ws2(k0-255 from H2) + W1-h1 + Ws1-h1 ------
    {
        f32x4 t1[2][2] = {}, t2[2][2] = {};
        mfma_tiles<2,2,8>(H1, 264, p.W2p,  16, 0, 2*wave, acc1);
        mfma_tiles<2,2,8>(H2, 264, p.Ws2p, 16, 0, 2*wave, acc2);
        mfma_tiles<2,2,8>(X,  264, p.W1p,  8, 0, 16 + 2*wave, t1);
        mfma_tiles<2,2,8>(X,  264, p.Ws1p, 8, 0, 16 + 2*wave, t2);
        __syncthreads();
#pragma unroll
        for (int t = 0; t < 2; ++t) {
            store2_bf16(t1[t], H1, 264, (2*wave + t)*16, p.b1  + 256, 256, true);
            store2_bf16(t2[t], H2, 264, (2*wave + t)*16, p.bs1 + 256, 256, true);
        }
        __syncthreads();
    }

    // ---- I3: W2(k256-511) + Ws2(k256-511) -----------------------------------
    mfma_tiles<2,2,8>(H1, 264, p.W2p,  16, 8, 2*wave, acc1);
    mfma_tiles<2,2,8>(H2, 264, p.Ws2p, 16, 8, 2*wave, acc2);
    __syncthreads();
#pragma unroll
    for (int t = 0; t < 2; ++t)
        store2_bf16(acc2[t], H1, 264, (2*wave + t)*16, p.bs2, 256, true);   // s2_2 -> H1
    __syncthreads();

    // ---- I4: Ws3(H1) + Wg1-h0/h1 (obs direct) -------------------------------
    {
        f32x4 s3[1][2] = {}, g0[2][2] = {}, g1[2][2] = {};
        mfma_tiles<1,2,8>(H1, 264, p.Ws3p, 8, 0, wave, s3);
        mfma_obsA2<2,4>(p.obs, b0, 256, p.Wg1p, 4, 2*wave,      g0);
        mfma_obsA2<2,4>(p.obs, b0, 256, p.Wg1p, 4, 16 + 2*wave, g1);
        __syncthreads();
        store2_bf16(s3[0], H1, 264, wave*16, p.bs3, 128, true);             // sg lo -> H1[:,0:128]
#pragma unroll
        for (int t = 0; t < 2; ++t) {
            store2_bf16(g0[t], H2, 264, (2*wave + t)*16, p.bg1,       256, true);
            store2_bf16(g1[t], X,  264, (2*wave + t)*16, p.bg1 + 256, 256, true);
        }
        __syncthreads();
    }

    // ---- I5: Wg2 (k0-255 from H2, k256-511 from X) --------------------------
    {
        f32x4 accg[2][2] = {};
        mfma_tiles<2,2,8>(H2, 264, p.Wg2p, 16, 0, 2*wave, accg);
        mfma_tiles<2,2,8>(X,  264, p.Wg2p, 16, 8, 2*wave, accg);
        __syncthreads();
#pragma unroll
        for (int t = 0; t < 2; ++t)
            store2_bf16(accg[t], H2, 264, (2*wave + t)*16, p.bg2, 256, true); // g2_2 -> H2
        __syncthreads();
    }

    // ---- I6: Wg3(H2) -> sg hi; park s1' (acc1) -> X (bufA) ------------------
    {
        f32x4 g3[1][2] = {};
        mfma_tiles<1,2,8>(H2, 264, p.Wg3p, 8, 0, wave, g3);
        // H1 hi-cols fresh, X readers (I5) done one barrier ago: no pre-bar
        store2_bf16(g3[0], H1 + 128, 264, wave*16, p.bg3, 128, true);
#pragma unroll
        for (int t = 0; t < 2; ++t)
            store2_bf16(acc1[t], X, 264, (2*wave + t)*16, p.b2, 256, true);   // bufA
        __syncthreads();
    }

    // ---- I7: gate(H1) on wave0 + Wp1(pp=0) from X; init sums ----------------
    {
        f32x4 th[2][2] = {};
        mfma_tiles<2,2,8>(X, 264, p.Wp1p, 8, 0, 2*wave, th);
        if (wave == 0) {
            f32x4 a6[1][2] = {};
            mfma_tiles<1,2,8>(H1, 264, p.Wgatep, 8, 0, 0, a6);
            if (r < 8) {
                float bv = p.bgate[r];
#pragma unroll
                for (int mt = 0; mt < 2; ++mt)
#pragma unroll
                    for (int i = 0; i < 4; ++i)
                        wgate[(mt*16 + q*4 + i)*8 + r] = expf(a6[0][mt][i] + bv);
            }
        }
        // H2 readers (I6) done; th0 -> H2, no pre-bar
#pragma unroll
        for (int t = 0; t < 2; ++t)
            store2_bf16(th[t], H2, 264, (2*wave + t)*16, p.bp1, 256, true);
        for (int i = tid; i < 32*40; i += 512) sums[i] = 0.f;
        __syncthreads();
    }

    // ---- J(pp): Wp2(pp) from H_cur  ||  Wp1(pp+1) from X -> H_next ----------
    for (int pp = 0; pp < 8; ++pp) {
        unsigned short* Hcur  = (pp & 1) ? H1 : H2;
        unsigned short* Hnext = (pp & 1) ? H2 : H1;
        if (wave < 3) {
            f32x4 aps[1][2] = {};
            mfma_tiles<1,2,8>(Hcur, 264, p.Wp2p + pp*12288, 8, 0, wave, aps);
            int col = wave*16 + r;
            float bv = (col < 40) ? p.bp2[pp*40 + col] : 0.f;
            if (col < 48) {
#pragma unroll
                for (int mt = 0; mt < 2; ++mt)
#pragma unroll
                    for (int i = 0; i < 4; ++i)
                        psbuf[(mt*16 + q*4 + i)*48 + col] = aps[0][mt][i] + bv;
            }
        }
        f32x4 th[2][2] = {};
        if (pp < 7)
            mfma_tiles<2,2,8>(X, 264, p.Wp1p + (pp+1)*65536, 8, 0, 2*wave, th);
        __syncthreads();
        if (pp < 7) {
#pragma unroll
            for (int t = 0; t < 2; ++t)
                store2_bf16(th[t], Hnext, 264, (2*wave + t)*16, p.bp1 + (pp+1)*256, 256, true);
        }
        for (int i = tid; i < 32*20; i += 512) {
            int b = i / 20, j = i - b*20;
            float invv = wgate[b*8 + pp] * expf(-psbuf[b*48 + 20 + j]);
            sums[b*40 + j]      += psbuf[b*48 + j] * invv;
            sums[b*40 + 20 + j] += invv;
        }
        __syncthreads();
    }

    // ---- Output: log_prob / entropy ----------------------------------------
    if (tid < 32) {
        int gb = b0 + tid;
        float lp = 0.f, sl = 0.f;
#pragma unroll
        for (int j = 0; j < 20; ++j) {
            float s2v = sums[tid*40 + 20 + j];
            float s1v = sums[tid*40 + j];
            float av  = p.actions[(size_t)gb*20 + j];
            float z   = av*s2v - s1v;
            float L   = logf(s2v);
            lp += -0.5f*z*z + L;
            sl += L;
        }
        p.out[(size_t)gb*2 + 0] = lp - 20.f*0.91893853320467274f;
        p.out[(size_t)gb*2 + 1] = 20.f*1.41893853320467274f - sl;
    }
}

// ---------------------------------------------------------------------------
extern "C" void kernel_launch(void* const* d_in, const int* in_sizes, int n_in,
                              void* d_out, int out_size, void* d_ws, size_t ws_size,
                              hipStream_t stream)
{
    const float* obs     = (const float*)d_in[0];
    const float* actions = (const float*)d_in[1];
    const float* W1  = (const float*)d_in[2];  const float* b1  = (const float*)d_in[3];
    const float* W2  = (const float*)d_in[4];  const float* b2  = (const float*)d_in[5];
    const float* Wp1 = (const float*)d_in[6];  const float* bp1 = (const float*)d_in[7];
    const float* Wp2 = (const float*)d_in[8];  const float* bp2 = (const float*)d_in[9];
    const float* Ws1 = (const float*)d_in[10]; const float* bs1 = (const float*)d_in[11];
    const float* Ws2 = (const float*)d_in[12]; const float* bs2 = (const float*)d_in[13];
    const float* Ws3 = (const float*)d_in[14]; const float* bs3 = (const float*)d_in[15];
    const float* Wg1 = (const float*)d_in[16]; const float* bg1 = (const float*)d_in[17];
    const float* Wg2 = (const float*)d_in[18]; const float* bg2 = (const float*)d_in[19];
    const float* Wg3 = (const float*)d_in[20]; const float* bg3 = (const float*)d_in[21];
    const float* Wgate = (const float*)d_in[22]; const float* bgate = (const float*)d_in[23];

    unsigned short* wp = (unsigned short*)d_ws;

    pack_weights<<<690, 256, 0, stream>>>(W1, W2, Wp1, Wp2, Ws1, Ws2, Ws3,
                                          Wg1, Wg2, Wg3, Wgate, wp);

    Params P;
    P.obs = obs; P.actions = actions; P.out = (float*)d_out;
    P.b1 = b1; P.b2 = b2; P.bp1 = bp1; P.bp2 = bp2;
    P.bs1 = bs1; P.bs2 = bs2; P.bs3 = bs3;
    P.bg1 = bg1; P.bg2 = bg2; P.bg3 = bg3; P.bgate = bgate;
    P.W1p = wp;            P.W2p = wp + 131072;  P.Wp1p = wp + 262144;
    P.Wp2p = wp + 786432;  P.Ws1p = wp + 884736; P.Ws2p = wp + 1015808;
    P.Ws3p = wp + 1146880; P.Wg1p = wp + 1179648; P.Wg2p = wp + 1245184;
    P.Wg3p = wp + 1376256; P.Wgatep = wp + 1409024;

    actor_fused<<<2048, 512, 0, stream>>>(P);
}

// Round 7
// 479.699 us; speedup vs baseline: 1.1427x; 1.1427x over previous
//
#include <hip/hip_runtime.h>
#include <cstdint>
#include <cstddef>

typedef __attribute__((ext_vector_type(8))) short short8_t;
typedef __attribute__((ext_vector_type(4))) float f32x4;

#define DEV __device__ __forceinline__

DEV unsigned short f2bf(float f) {
    unsigned u = __float_as_uint(f);
    u += 0x7FFFu + ((u >> 16) & 1u);   // round-to-nearest-even
    return (unsigned short)(u >> 16);
}

// ---------------------------------------------------------------------------
// Weight packing: fp32 row-major (K x N) -> bf16 MFMA-B fragment order.
// ---------------------------------------------------------------------------
__global__ void pack_weights(const float* W1, const float* W2,
                             const float* Wp1, const float* Wp2,
                             const float* Ws1, const float* Ws2, const float* Ws3,
                             const float* Wg1, const float* Wg2, const float* Wg3,
                             const float* Wgate, unsigned short* out)
{
    int c = blockIdx.x * 256 + threadIdx.x;
    if (c >= 176640) return;
    const float* src; int K, N; size_t dstoff; int lc = c;
    if      (c <  16384) { src = W1;  K=256; N=512; dstoff = 0; }
    else if (c <  32768) { lc = c-16384;  src = W2;  K=512; N=256; dstoff = 131072; }
    else if (c <  98304) { lc = c-32768;  int p = lc/8192; lc -= p*8192;
                           src = Wp1 + (size_t)p*65536; K=256; N=256;
                           dstoff = 262144 + (size_t)p*65536; }
    else if (c < 110592) { lc = c-98304;  int p = lc/1536; lc -= p*1536;
                           src = Wp2 + (size_t)p*10240; K=256; N=40;
                           dstoff = 786432 + (size_t)p*12288; }
    else if (c < 126976) { lc = c-110592; src = Ws1; K=256; N=512; dstoff = 884736; }
    else if (c < 143360) { lc = c-126976; src = Ws2; K=512; N=256; dstoff = 1015808; }
    else if (c < 147456) { lc = c-143360; src = Ws3; K=256; N=128; dstoff = 1146880; }
    else if (c < 155648) { lc = c-147456; src = Wg1; K=128; N=512; dstoff = 1179648; }
    else if (c < 172032) { lc = c-155648; src = Wg2; K=512; N=256; dstoff = 1245184; }
    else if (c < 176128) { lc = c-172032; src = Wg3; K=256; N=128; dstoff = 1376256; }
    else                 { lc = c-176128; src = Wgate; K=256; N=8;  dstoff = 1409024; }
    int lane = lc & 63, tkb = lc >> 6;
    int KB = K >> 5;
    int kb = tkb % KB, t = tkb / KB;
    int n  = t*16 + (lane & 15);
    int k0 = kb*32 + (lane >> 4)*8;
    unsigned short e[8];
#pragma unroll
    for (int j = 0; j < 8; ++j) {
        float v = (n < N) ? src[(size_t)(k0 + j)*N + n] : 0.f;
        e[j] = f2bf(v);
    }
    uint4 o;
    o.x = (unsigned)e[0] | ((unsigned)e[1] << 16);
    o.y = (unsigned)e[2] | ((unsigned)e[3] << 16);
    o.z = (unsigned)e[4] | ((unsigned)e[5] << 16);
    o.w = (unsigned)e[6] | ((unsigned)e[7] << 16);
    *reinterpret_cast<uint4*>(out + dstoff + (size_t)lc*8) = o;
}

// ---------------------------------------------------------------------------
struct Params {
    const float *obs, *actions;
    const float *b1, *b2, *bp1, *bp2, *bs1, *bs2, *bs3, *bg1, *bg2, *bg3, *bgate;
    const unsigned short *W1p, *W2p, *Wp1p, *Wp2p, *Ws1p, *Ws2p, *Ws3p,
                         *Wg1p, *Wg2p, *Wg3p, *Wgatep;
    float* out;
};

// A from LDS (bf16, stride xs elems), B from packed global. 32-bit flat
// addressing (R5 evidence: removes address-chain spills under (512,4)).
template<int NTW, int NMT, int NKB>
DEV void mfma_tiles(const unsigned short* X, int xs,
                    const unsigned short* wp, int nkbtot, int kbstart,
                    int nt0, f32x4 (&acc)[NTW][NMT])
{
    const int lane = threadIdx.x & 63;
    const int q = lane >> 4, r = lane & 15;
    const short8_t* __restrict__ W8 = (const short8_t*)wp;
    const short8_t* __restrict__ X8 = (const short8_t*)X;
    const int xrow = xs >> 3;
    const int bbase = (nt0*nkbtot + kbstart)*64 + lane;
#pragma unroll
    for (int kb = 0; kb < NKB; ++kb) {
        short8_t a[NMT];
#pragma unroll
        for (int mt = 0; mt < NMT; ++mt)
            a[mt] = X8[(r + 16*mt)*xrow + kb*4 + q];
#pragma unroll
        for (int t = 0; t < NTW; ++t) {
            short8_t b = W8[bbase + (t*nkbtot + kb)*64];
#pragma unroll
            for (int mt = 0; mt < NMT; ++mt)
                acc[t][mt] = __builtin_amdgcn_mfma_f32_16x16x32_bf16(a[mt], b, acc[t][mt], 0, 0, 0);
        }
    }
}

// A built in-register from fp32 global obs (3 row-slabs), row-clamped.
template<int NTW, int NKB>
DEV void mfma_obsA3(const float* obs, int b0, int colbase,
                    const unsigned short* wp, int nkbtot, int nt0,
                    f32x4 (&acc)[NTW][3])
{
    const int lane = threadIdx.x & 63;
    const int q = lane >> 4, r = lane & 15;
    const short8_t* __restrict__ W8 = (const short8_t*)wp;
    const int bbase = nt0*nkbtot*64 + lane;
#pragma unroll
    for (int kb = 0; kb < NKB; ++kb) {
        short8_t a[3];
#pragma unroll
        for (int mt = 0; mt < 3; ++mt) {
            int rowg = b0 + mt*16 + r; if (rowg > 65535) rowg = 65535;
            const float* s = obs + (size_t)rowg*384 + colbase + kb*32 + q*8;
            float4 v0 = *reinterpret_cast<const float4*>(s);
            float4 v1 = *reinterpret_cast<const float4*>(s + 4);
            a[mt] = short8_t{ (short)f2bf(v0.x),(short)f2bf(v0.y),(short)f2bf(v0.z),(short)f2bf(v0.w),
                              (short)f2bf(v1.x),(short)f2bf(v1.y),(short)f2bf(v1.z),(short)f2bf(v1.w) };
        }
#pragma unroll
        for (int t = 0; t < NTW; ++t) {
            short8_t b = W8[bbase + (t*nkbtot + kb)*64];
#pragma unroll
            for (int mt = 0; mt < 3; ++mt)
                acc[t][mt] = __builtin_amdgcn_mfma_f32_16x16x32_bf16(a[mt], b, acc[t][mt], 0, 0, 0);
        }
    }
}

// store one n-tile (NMT m-slabs) to bf16 LDS, bias + optional leaky-relu
template<int NMT>
DEV void storeN(const f32x4 (&a)[NMT], unsigned short* dst, int os, int col0,
                const float* bias, int Nreal, bool lrelu)
{
    const int lane = threadIdx.x & 63;
    const int q = lane >> 4, r = lane & 15;
    const int col = col0 + r;
    float bv = (col < Nreal) ? bias[col] : 0.f;
#pragma unroll
    for (int mt = 0; mt < NMT; ++mt)
#pragma unroll
        for (int i = 0; i < 4; ++i) {
            float v = a[mt][i] + bv;
            if (lrelu) v = v > 0.f ? v : 0.01f*v;
            dst[(mt*16 + q*4 + i)*os + col] = f2bf(v);
        }
}

// ---------------------------------------------------------------------------
// R5 schedule, 48 rows/block (NMT=3): B-fragment reuse x1.5 -> L2 weight
// traffic x2/3 (the binding resource). 512 thr / 8 waves; LDS 77568 B ->
// 2 blocks/CU -> 16 waves/CU. (512,4) hard 128-reg budget (R2/R5/R6 evidence).
#define ROWS 48
#define XS   264
__global__ __launch_bounds__(512, 4) void actor_fused(Params p)
{
    __shared__ __align__(16) unsigned char smem[77568];
    unsigned short* X       = (unsigned short*)(smem);           // 48x264: xStat -> sg -> psbuf/sums
    unsigned short* bufA    = (unsigned short*)(smem + 25344);   // 48x264: s1'
    unsigned short* halfbuf = (unsigned short*)(smem + 50688);   // 48x264
    float*          psbuf   = (float*)(smem);                    // 48x48 f32 (alias X, post-gate)
    float*          sums    = (float*)(smem + 9216);             // 48x40 f32 (alias X)
    float*          wgate   = (float*)(smem + 76032);            // 48x8 f32 (own slot)

    const int tid  = threadIdx.x;
    const int wave = tid >> 6;
    const int lane = tid & 63, q = lane >> 4, r = lane & 15;
    const int b0   = blockIdx.x * ROWS;

    // ---- P1: load obs stat cols -> X ---------------------------------------
    for (int i = tid; i < ROWS*64; i += 512) {
        int rr = i >> 6, c4 = i & 63;
        float4 v = {0.f,0.f,0.f,0.f};
        if (b0 + rr < 65536)
            v = *reinterpret_cast<const float4*>(p.obs + (size_t)(b0 + rr)*384 + c4*4);
        unsigned short* d = X + rr*XS + c4*4;
        d[0]=f2bf(v.x); d[1]=f2bf(v.y); d[2]=f2bf(v.z); d[3]=f2bf(v.w);
    }
    __syncthreads();

    // ---- P2: s1' = lrelu(lrelu(X@W1+b1)@W2+b2) -> bufA ---------------------
    f32x4 acc1[2][3] = {};
    for (int h = 0; h < 2; ++h) {
        f32x4 t1[2][3] = {};
        mfma_tiles<2,3,8>(X, XS, p.W1p, 8, 0, 16*h + 2*wave, t1);
        __syncthreads();
#pragma unroll
        for (int t = 0; t < 2; ++t)
            storeN<3>(t1[t], halfbuf, XS, (2*wave + t)*16, p.b1 + 256*h, 256, true);
        __syncthreads();
        mfma_tiles<2,3,8>(halfbuf, XS, p.W2p, 16, 8*h, 2*wave, acc1);
    }
    __syncthreads();
#pragma unroll
    for (int t = 0; t < 2; ++t)
        storeN<3>(acc1[t], bufA, XS, (2*wave + t)*16, p.b2, 256, true);

    // ---- P3: s2 chain -> sg lo (X cols 0..127) -----------------------------
    f32x4 acc2[2][3] = {};
    for (int h = 0; h < 2; ++h) {
        f32x4 t2[2][3] = {};
        mfma_tiles<2,3,8>(X, XS, p.Ws1p, 8, 0, 16*h + 2*wave, t2);
        __syncthreads();
#pragma unroll
        for (int t = 0; t < 2; ++t)
            storeN<3>(t2[t], halfbuf, XS, (2*wave + t)*16, p.bs1 + 256*h, 256, true);
        __syncthreads();
        mfma_tiles<2,3,8>(halfbuf, XS, p.Ws2p, 16, 8*h, 2*wave, acc2);
    }
    __syncthreads();
#pragma unroll
    for (int t = 0; t < 2; ++t)
        storeN<3>(acc2[t], halfbuf, XS, (2*wave + t)*16, p.bs2, 256, true);  // s2_2
    __syncthreads();
    {
        f32x4 a3[1][3] = {};
        mfma_tiles<1,3,8>(halfbuf, XS, p.Ws3p, 8, 0, wave, a3);
        storeN<3>(a3[0], X, XS, wave*16, p.bs3, 128, true);   // sg lo (X stat-reads done)
    }
    __syncthreads();

    // ---- P4: g2 chain (goal A direct from obs) -> sg hi (X cols 128..255) --
    f32x4 acc4[2][3] = {};
    for (int h = 0; h < 2; ++h) {
        f32x4 t3[2][3] = {};
        mfma_obsA3<2,4>(p.obs, b0, 256, p.Wg1p, 4, 16*h + 2*wave, t3);
        __syncthreads();
#pragma unroll
        for (int t = 0; t < 2; ++t)
            storeN<3>(t3[t], halfbuf, XS, (2*wave + t)*16, p.bg1 + 256*h, 256, true);
        __syncthreads();
        mfma_tiles<2,3,8>(halfbuf, XS, p.Wg2p, 16, 8*h, 2*wave, acc4);
    }
    __syncthreads();
#pragma unroll
    for (int t = 0; t < 2; ++t)
        storeN<3>(acc4[t], halfbuf, XS, (2*wave + t)*16, p.bg2, 256, true);  // g2_2
    __syncthreads();
    {
        f32x4 a5[1][3] = {};
        mfma_tiles<1,3,8>(halfbuf, XS, p.Wg3p, 8, 0, wave, a5);
        storeN<3>(a5[0], X + 128, XS, wave*16, p.bg3, 128, true);  // sg hi
    }
    __syncthreads();

    // ---- P5: w_gate = exp(sg@Wgate + bgate), waves 0..2 (one slab each) ----
    if (wave < 3) {
        f32x4 g[1][1] = {};
        mfma_tiles<1,1,8>(X + wave*16*XS, XS, p.Wgatep, 8, 0, 0, g);
        if (r < 8) {
            float bv = p.bgate[r];
#pragma unroll
            for (int i = 0; i < 4; ++i)
                wgate[(wave*16 + q*4 + i)*8 + r] = expf(g[0][0][i] + bv);
        }
    }
    __syncthreads();

    // ---- P6: primitive loop ------------------------------------------------
    for (int i = tid; i < ROWS*40; i += 512) sums[i] = 0.f;   // X dead post-gate
    __syncthreads();

    for (int pp = 0; pp < 8; ++pp) {
        f32x4 th[2][3] = {};
        mfma_tiles<2,3,8>(bufA, XS, p.Wp1p + pp*65536, 8, 0, 2*wave, th);
#pragma unroll
        for (int t = 0; t < 2; ++t)
            storeN<3>(th[t], halfbuf, XS, (2*wave + t)*16, p.bp1 + pp*256, 256, true);
        __syncthreads();
        if (wave < 3) {
            f32x4 aps[1][3] = {};
            mfma_tiles<1,3,8>(halfbuf, XS, p.Wp2p + pp*12288, 8, 0, wave, aps);
            int col = wave*16 + r;
            float bv = (col < 40) ? p.bp2[pp*40 + col] : 0.f;
#pragma unroll
            for (int mt = 0; mt < 3; ++mt)
#pragma unroll
                for (int i = 0; i < 4; ++i)
                    psbuf[(mt*16 + q*4 + i)*48 + col] = aps[0][mt][i] + bv;
        }
        __syncthreads();
        for (int i = tid; i < ROWS*20; i += 512) {
            int b = i / 20, j = i - b*20;
            float invv = wgate[b*8 + pp] * expf(-psbuf[b*48 + 20 + j]);
            sums[b*40 + j]      += psbuf[b*48 + j] * invv;
            sums[b*40 + 20 + j] += invv;
        }
        __syncthreads();
    }

    // ---- P7: log_prob / entropy --------------------------------------------
    if (tid < ROWS) {
        int gb = b0 + tid;
        if (gb < 65536) {
            float lp = 0.f, sl = 0.f;
#pragma unroll
            for (int j = 0; j < 20; ++j) {
                float s2v = sums[tid*40 + 20 + j];
                float s1v = sums[tid*40 + j];
                float av  = p.actions[(size_t)gb*20 + j];
                float z   = av*s2v - s1v;
                float L   = logf(s2v);
                lp += -0.5f*z*z + L;
                sl += L;
            }
            p.out[(size_t)gb*2 + 0] = lp - 20.f*0.91893853320467274f;
            p.out[(size_t)gb*2 + 1] = 20.f*1.41893853320467274f - sl;
        }
    }
}

// ---------------------------------------------------------------------------
extern "C" void kernel_launch(void* const* d_in, const int* in_sizes, int n_in,
                              void* d_out, int out_size, void* d_ws, size_t ws_size,
                              hipStream_t stream)
{
    const float* obs     = (const float*)d_in[0];
    const float* actions = (const float*)d_in[1];
    const float* W1  = (const float*)d_in[2];  const float* b1  = (const float*)d_in[3];
    const float* W2  = (const float*)d_in[4];  const float* b2  = (const float*)d_in[5];
    const float* Wp1 = (const float*)d_in[6];  const float* bp1 = (const float*)d_in[7];
    const float* Wp2 = (const float*)d_in[8];  const float* bp2 = (const float*)d_in[9];
    const float* Ws1 = (const float*)d_in[10]; const float* bs1 = (const float*)d_in[11];
    const float* Ws2 = (const float*)d_in[12]; const float* bs2 = (const float*)d_in[13];
    const float* Ws3 = (const float*)d_in[14]; const float* bs3 = (const float*)d_in[15];
    const float* Wg1 = (const float*)d_in[16]; const float* bg1 = (const float*)d_in[17];
    const float* Wg2 = (const float*)d_in[18]; const float* bg2 = (const float*)d_in[19];
    const float* Wg3 = (const float*)d_in[20]; const float* bg3 = (const float*)d_in[21];
    const float* Wgate = (const float*)d_in[22]; const float* bgate = (const float*)d_in[23];

    unsigned short* wp = (unsigned short*)d_ws;

    pack_weights<<<690, 256, 0, stream>>>(W1, W2, Wp1, Wp2, Ws1, Ws2, Ws3,
                                          Wg1, Wg2, Wg3, Wgate, wp);

    Params P;
    P.obs = obs; P.actions = actions; P.out = (float*)d_out;
    P.b1 = b1; P.b2 = b2; P.bp1 = bp1; P.bp2 = bp2;
    P.bs1 = bs1; P.bs2 = bs2; P.bs3 = bs3;
    P.bg1 = bg1; P.bg2 = bg2; P.bg3 = bg3; P.bgate = bgate;
    P.W1p = wp;            P.W2p = wp + 131072;  P.Wp1p = wp + 262144;
    P.Wp2p = wp + 786432;  P.Ws1p = wp + 884736; P.Ws2p = wp + 1015808;
    P.Ws3p = wp + 1146880; P.Wg1p = wp + 1179648; P.Wg2p = wp + 1245184;
    P.Wg3p = wp + 1376256; P.Wgatep = wp + 1409024;

    actor_fused<<<(65536 + ROWS - 1)/ROWS, 512, 0, stream>>>(P);
}